// Round 2
// 796.296 us; speedup vs baseline: 1.2316x; 1.2316x over previous
//
#include <hip/hip_runtime.h>
#include <cstdint>

// Problem constants (MicroCortexMLA): B=2, S=2048, H=2048, NH=16,
// NOPE=128, ROPE=64, VD=128, QLORA=1536, KVLORA=512, theta=1e6, eps=1e-6
// Harness dtypes: fp32 inputs (converted to bf16 in ws), int32 pos, fp32 out.
#define S_LEN 2048
#define NH_N  16

typedef short s16x8 __attribute__((ext_vector_type(8)));
typedef unsigned short u16x8 __attribute__((ext_vector_type(8)));
typedef float f32x4 __attribute__((ext_vector_type(4)));

__device__ __forceinline__ float b2f(unsigned short u) {
    return __uint_as_float(((uint32_t)u) << 16);
}
// round-to-nearest-even f32 -> bf16
__device__ __forceinline__ unsigned short f2b(float f) {
    uint32_t x = __float_as_uint(f);
    x += 0x7fffu + ((x >> 16) & 1u);
    return (unsigned short)(x >> 16);
}

__device__ __forceinline__ void cstore(unsigned short* p, float v) { *p = f2b(v); }
__device__ __forceinline__ void cstore(float* p, float v) { *p = v; }

// async global->LDS DMA, 16B per lane. LDS dst is wave-uniform base; HW adds
// lane*16. Tracked by vmcnt; __syncthreads() drains it.
__device__ __forceinline__ void gl2lds16(const void* g, void* l) {
    __builtin_amdgcn_global_load_lds(
        (const __attribute__((address_space(1))) unsigned int*)g,
        (__attribute__((address_space(3))) unsigned int*)l, 16, 0, 0);
}

// ---------------------------------------------------------------------------
// fp32 -> bf16 conversion, vectorized x4, grid-stride. n % 4 == 0.
// ---------------------------------------------------------------------------
__global__ __launch_bounds__(256) void f32_to_bf16(const float* __restrict__ in,
                                                   unsigned short* __restrict__ out,
                                                   long n)
{
    const long nv = n >> 2;
    long i = (long)blockIdx.x * blockDim.x + threadIdx.x;
    const long stride = (long)gridDim.x * blockDim.x;
    for (; i < nv; i += stride) {
        float4 v = ((const float4*)in)[i];
        ushort4 o;
        o.x = f2b(v.x); o.y = f2b(v.y); o.z = f2b(v.z); o.w = f2b(v.w);
        ((ushort4*)out)[i] = o;
    }
}

// ---------------------------------------------------------------------------
// C = A @ B^T, m97-style: 128x128 block tile, BK=32, LDS staged via
// global_load_lds (16B/lane), 2-barrier K-loop. block 256 = 4 waves; wave w
// computes 64x64 at (w>>1, w&1) quadrant = 4x4 MFMA accs.
// LDS granule swizzle: position gp of row holds source granule
// gp ^ ((row ^ (row>>2)) & 3)  -> frag ds_read_b128 2-way max (free).
// Stores guarded by col < Nlim (B rows beyond N read adjacent ws, harmless).
// Batched over blockIdx.z = b*16+h. M%128==0, K%32==0, 16B alignment.
// ---------------------------------------------------------------------------
template <typename CT>
__global__ __launch_bounds__(256) void gemm128(
    const unsigned short* __restrict__ A, const unsigned short* __restrict__ B,
    CT* __restrict__ C,
    int K, int lda, int ldb, int ldc, int Nlim,
    long sAb, long sAh, long sBb, long sBh, long sCb, long sCh)
{
    __shared__ unsigned short Alds[128 * 32];
    __shared__ unsigned short Blds[128 * 32];
    const int z = blockIdx.z, b = z >> 4, h = z & 15;
    A += (long)b * sAb + (long)h * sAh;
    B += (long)b * sBb + (long)h * sBh;
    C += (long)b * sCb + (long)h * sCh;
    const int tid = threadIdx.x;
    const int lane = tid & 63, w = tid >> 6;
    const int l15 = lane & 15, q4 = lane >> 4;
    const int m0 = blockIdx.x * 128, n0 = blockIdx.y * 128;
    const int wm = (w >> 1) * 64, wn = (w & 1) * 64;

    // per-thread staging constants (2 granules per tile)
    int srow[2], sgc[2];
#pragma unroll
    for (int it = 0; it < 2; ++it) {
        const int g = it * 256 + tid;
        const int row = g >> 2, gp = g & 3;
        srow[it] = row;
        sgc[it] = gp ^ ((row ^ (row >> 2)) & 3);
    }
    // per-thread frag read offsets
    int aoff[4], boff[4];
#pragma unroll
    for (int i = 0; i < 4; ++i) {
        const int ra = wm + i * 16 + l15;
        aoff[i] = ra * 32 + (q4 ^ ((ra ^ (ra >> 2)) & 3)) * 8;
        const int rb = wn + i * 16 + l15;
        boff[i] = rb * 32 + (q4 ^ ((rb ^ (rb >> 2)) & 3)) * 8;
    }

    f32x4 acc[4][4];
#pragma unroll
    for (int i = 0; i < 4; ++i)
#pragma unroll
        for (int j = 0; j < 4; ++j) acc[i][j] = (f32x4){0.f, 0.f, 0.f, 0.f};

    for (int k0 = 0; k0 < K; k0 += 32) {
        __syncthreads();  // previous iter's frag reads done
#pragma unroll
        for (int it = 0; it < 2; ++it) {
            gl2lds16(A + (long)(m0 + srow[it]) * lda + k0 + sgc[it] * 8,
                     (char*)Alds + ((it * 256 + w * 64) << 4));
            gl2lds16(B + (long)(n0 + srow[it]) * ldb + k0 + sgc[it] * 8,
                     (char*)Blds + ((it * 256 + w * 64) << 4));
        }
        __syncthreads();  // drain DMA
        s16x8 af[4], bf[4];
#pragma unroll
        for (int i = 0; i < 4; ++i) {
            af[i] = *(const s16x8*)(Alds + aoff[i]);
            bf[i] = *(const s16x8*)(Blds + boff[i]);
        }
#pragma unroll
        for (int i = 0; i < 4; ++i)
#pragma unroll
            for (int j = 0; j < 4; ++j)
                acc[i][j] = __builtin_amdgcn_mfma_f32_16x16x32_bf16(af[i], bf[j], acc[i][j], 0, 0, 0);
    }

#pragma unroll
    for (int i = 0; i < 4; ++i) {
        const int row0 = m0 + wm + i * 16 + q4 * 4;
#pragma unroll
        for (int j = 0; j < 4; ++j) {
            const int col = n0 + wn + j * 16 + l15;
            if (col < Nlim) {
#pragma unroll
                for (int r = 0; r < 4; ++r)
                    cstore(&C[(long)(row0 + r) * ldc + col], acc[i][j][r]);
            }
        }
    }
}

// ---------------------------------------------------------------------------
// In-place RMSNorm over rows of 1536, one block per row.
// ---------------------------------------------------------------------------
__global__ __launch_bounds__(256) void rmsnorm_k(unsigned short* __restrict__ ql,
                                                 const unsigned short* __restrict__ w)
{
    const long base = (long)blockIdx.x * 1536;
    const int tid = threadIdx.x;
    float v[6];
    float ss = 0.f;
#pragma unroll
    for (int i = 0; i < 6; ++i) {
        v[i] = b2f(ql[base + tid + i * 256]);
        ss += v[i] * v[i];
    }
#pragma unroll
    for (int off = 32; off; off >>= 1) ss += __shfl_xor(ss, off, 64);
    __shared__ float red[4];
    if ((tid & 63) == 0) red[tid >> 6] = ss;
    __syncthreads();
    const float tot = red[0] + red[1] + red[2] + red[3];
    const float r = rsqrtf(tot * (1.0f / 1536.0f) + 1e-6f);
#pragma unroll
    for (int i = 0; i < 6; ++i) {
        const int idx = tid + i * 256;
        ql[base + idx] = f2b(v[i] * r * b2f(w[idx]));
    }
}

// ---------------------------------------------------------------------------
// RoPE for q (per head) and k (reference's permuted layout, consistent q/k).
// ---------------------------------------------------------------------------
__global__ __launch_bounds__(512) void rope_k(
    const unsigned short* __restrict__ q, const unsigned short* __restrict__ ckv,
    const int* __restrict__ pos_ids,
    unsigned short* __restrict__ q_rope, unsigned short* __restrict__ krope)
{
    const int bs = blockIdx.x;
    const int b = bs >> 11, s = bs & 2047;
    const int t = threadIdx.x;
    const int j = t & 31, h = t >> 5;
    const float pos = (float)pos_ids[bs];
    const float invf = __expf(-(float)j * 0.4317347f);  // ln(1e6)/32
    float sn, cs;
    sincosf(pos * invf, &sn, &cs);
    const unsigned short* x = q + (long)bs * 3072 + h * 192 + 128;
    const float x0 = b2f(x[2 * j]), x1 = b2f(x[2 * j + 1]);
    const long ob = ((long)(b * NH_N + h) * S_LEN + s) * 64;
    q_rope[ob + j]      = f2b(x0 * cs - x1 * sn);
    q_rope[ob + 32 + j] = f2b(x1 * cs + x0 * sn);
    if (h == 0) {
        const unsigned short* y = ckv + (long)bs * 576 + 512;
        const float y0 = b2f(y[2 * j]), y1 = b2f(y[2 * j + 1]);
        const long ob2 = (long)bs * 64;
        krope[ob2 + j]      = f2b(y0 * cs - y1 * sn);
        krope[ob2 + 32 + j] = f2b(y1 * cs + y0 * sn);
    }
}

// qT[h][c][n] = Wkv_up[(h*256+n)*512 + c]
__global__ __launch_bounds__(256) void transpose_qabsorb(
    const unsigned short* __restrict__ Wkv_up, unsigned short* __restrict__ qT)
{
    const int idx = blockIdx.x * 256 + threadIdx.x;
    const int n = idx & 127;
    const int c = (idx >> 7) & 511;
    const int h = idx >> 16;
    qT[idx] = Wkv_up[((long)(h * 256 + n)) * 512 + c];
}

// ---------------------------------------------------------------------------
// VT_g[b][c][key] = ckv[b][key][c]  (c < 512) — V^T for the PV MFMA B-frags.
// Tiled 64x64 transpose through LDS. grid (32 keyblk, 8 cblk, 2 b).
// ---------------------------------------------------------------------------
__global__ __launch_bounds__(256) void transpose_ckv(
    const unsigned short* __restrict__ ckv, unsigned short* __restrict__ VT_g)
{
    __shared__ unsigned short t[64][72];  // +8 pad
    const int k0 = blockIdx.x * 64, c0 = blockIdx.y * 64, b = blockIdx.z;
    const int tid = threadIdx.x;
#pragma unroll
    for (int it = 0; it < 2; ++it) {
        int idx = tid + it * 256;  // 512 tasks: 64 rows x 8 granules
        int row = idx >> 3, g = idx & 7;
        *(s16x8*)&t[row][g * 8] =
            *(const s16x8*)(ckv + ((long)(b * S_LEN + k0 + row) * 576 + c0 + g * 8));
    }
    __syncthreads();
#pragma unroll
    for (int it = 0; it < 2; ++it) {
        int idx = tid + it * 256;  // 512 tasks: 64 c x 8 key-granules
        int c = idx >> 3, g = idx & 7;
        u16x8 v;
#pragma unroll
        for (int j = 0; j < 8; ++j) v[j] = t[g * 8 + j][c];
        *(u16x8*)(VT_g + ((long)(b * 512 + c0 + c) * S_LEN + k0 + g * 8)) = v;
    }
}

// ---------------------------------------------------------------------------
// MFMA flash attention in the 576-dim latent space (512 c + 64 rope).
// v2: 2-phase software pipeline (double-buffered LDS, prefetch tile kt+1
// while computing tile kt, ONE __syncthreads per tile whose implicit
// vmcnt(0) drain lands after ~2600 cyc of MFMA -> free).
//
// grid (32 bh, 8 y); block = 512 threads = 8 waves; each block processes the
// 128-row q-tile qt = 15-y then qt = y  => exactly 68 key-tiles per block for
// every y (perfect balance; 256 blocks = exactly 1/CU at 149.5 KB LDS).
//
// Wave w owns rows q0 + w*16 .. +16 for ALL 512 c (identical per-wave state
// to the verified v1: qf 18 frags + O 32 x f32x4; softmax fully private;
// P transpose via wave-private LDS, lgkmcnt only).
//
// __launch_bounds__(512, 1): occupancy is LDS-bound (1 block/CU = 2 waves/EU)
// regardless, so don't cap the unified VGPR+AGPR file at 256 — per-wave state
// (~240 regs) is at the edge and a forced cap risks scratch spill.
//
// K/VT tiles staged via global_load_lds in CONSUMPTION ORDER (slot =
// frag_index*64 + lane -> ds_read_b128 hits 64 consecutive granules, zero
// bank conflicts; DMA dst = uniform base + lane*16 maps linearly).
//   K slot idx: kb=idx>>7, h=(idx>>6)&1, q4s=(idx>>4)&3, l15s=idx&15
//     -> key = h*16+l15s, dim-granule g = kb*4+q4s  (g<64: ckv, else krope)
//   Staging rounds with 512 threads: K = 4 full rounds (idx<2048, all ckv)
//     + half-round tid<256 (idx 2048..2303, all krope)  -> no divergence.
//   VT slot idx: nb=idx>>6 -> c = nb*16 + (idx&15), key-granule (idx>>4)&3;
//     4 full rounds.
// Waves skip fully-masked diagonal tiles (k0 > q0+w*16+15): P==0 there.
// ---------------------------------------------------------------------------
__global__ __launch_bounds__(512, 1) void flash_mfma(
    const unsigned short* __restrict__ qabs,  const unsigned short* __restrict__ qrope,
    const unsigned short* __restrict__ ckv,   const unsigned short* __restrict__ krope,
    const unsigned short* __restrict__ VT_g,  unsigned short* __restrict__ attn_out)
{
    __shared__ unsigned short K_lds[2][2304 * 8];   // 2 x 36 KB, consumption order
    __shared__ unsigned short VT_lds[2][2048 * 8];  // 2 x 32 KB, consumption order
    __shared__ unsigned short P_lds[8][16 * 40];    // per-wave private, +8 pad

    const float scale = 0.07216878364870323f;  // 1/sqrt(192)
    const int tid = threadIdx.x;
    const int lane = tid & 63, w = tid >> 6;
    const int l15 = lane & 15, q4 = lane >> 4;
    const int bh = blockIdx.x;
    const int b = bh >> 4;

    const unsigned short* ckv_b  = ckv   + (long)b * S_LEN * 576;
    const unsigned short* krop_b = krope + (long)b * S_LEN * 64;
    const unsigned short* vt_b   = VT_g  + (long)b * 512 * S_LEN;

    // per-thread staging source offsets (bf16 elements)
    int koff[4], voff[4];
#pragma unroll
    for (int it = 0; it < 4; ++it) {
        const int idx = it * 512 + tid;
        const int key = ((idx >> 6) & 1) * 16 + (idx & 15);
        const int g   = (idx >> 7) * 4 + ((idx >> 4) & 3);   // < 64 for idx < 2048
        koff[it] = key * 576 + g * 8;
        const int c   = (idx >> 6) * 16 + (idx & 15);
        voff[it] = c * S_LEN + ((idx >> 4) & 3) * 8;
    }
    const int hoff = (((tid >> 6) & 1) * 16 + (tid & 15)) * 64 +
                     ((tid >> 7) * 4 + ((tid >> 4) & 3)) * 8;   // krope half-round

#pragma unroll 1
    for (int half = 0; half < 2; ++half) {
        const int qt = half ? blockIdx.y : 15 - blockIdx.y;
        const int q0 = qt * 128;

        // Q fragments: rows q0 + w*16 + l15, dims kb*32 + q4*8 (+j)
        s16x8 qf[18];
        {
            const unsigned short* qa = qabs + ((long)bh * S_LEN + q0 + w * 16 + l15) * 512 + q4 * 8;
#pragma unroll
            for (int kb = 0; kb < 16; ++kb) qf[kb] = *(const s16x8*)(qa + kb * 32);
            const unsigned short* qr = qrope + ((long)bh * S_LEN + q0 + w * 16 + l15) * 64 + q4 * 8;
            qf[16] = *(const s16x8*)(qr);
            qf[17] = *(const s16x8*)(qr + 32);
        }

        f32x4 O[32];
#pragma unroll
        for (int nb = 0; nb < 32; ++nb) O[nb] = (f32x4){0.f, 0.f, 0.f, 0.f};
        float m_i[4] = {-INFINITY, -INFINITY, -INFINITY, -INFINITY};
        float l_i[4] = {0.f, 0.f, 0.f, 0.f};

        const int nkt = 4 * qt + 4;
        unsigned short *Kc = K_lds[0], *Kn = K_lds[1];
        unsigned short *Vc = VT_lds[0], *Vn = VT_lds[1];

        // ---- prologue: stage tile 0 into current buffers ----
        {
#pragma unroll
            for (int it = 0; it < 4; ++it)
                gl2lds16(ckv_b + koff[it], (char*)Kc + ((it * 512 + w * 64) << 4));
            if (tid < 256)
                gl2lds16(krop_b + hoff, (char*)Kc + ((2048 + w * 64) << 4));
#pragma unroll
            for (int it = 0; it < 4; ++it)
                gl2lds16(vt_b + voff[it], (char*)Vc + ((it * 512 + w * 64) << 4));
        }
        __syncthreads();  // drain tile-0 DMA (+ qf loads)

        for (int kt = 0; kt < nkt; ++kt) {
            const int k0 = kt * 32;

            // ---- stage tile kt+1 into the other buffer (in flight under
            //      this tile's compute; drained by the barrier below) ----
            if (kt + 1 < nkt) {
                const int kn = k0 + 32;
                const unsigned short* cs = ckv_b + (long)kn * 576;
#pragma unroll
                for (int it = 0; it < 4; ++it)
                    gl2lds16(cs + koff[it], (char*)Kn + ((it * 512 + w * 64) << 4));
                if (tid < 256)
                    gl2lds16(krop_b + (long)kn * 64 + hoff, (char*)Kn + ((2048 + w * 64) << 4));
                const unsigned short* vs = vt_b + kn;
#pragma unroll
                for (int it = 0; it < 4; ++it)
                    gl2lds16(vs + voff[it], (char*)Vn + ((it * 512 + w * 64) << 4));
            }

            // ---- compute tile kt from current buffers (skip fully-masked) ----
            if (k0 <= q0 + (w << 4) + 15) {
                // S-phase: my 16 rows x 32 keys
                f32x4 s0 = {0.f, 0.f, 0.f, 0.f}, s1 = s0;
#pragma unroll
                for (int kb = 0; kb < 18; ++kb) {
                    s16x8 k0f = *(const s16x8*)&Kc[((kb * 2 + 0) * 64 + lane) * 8];
                    s16x8 k1f = *(const s16x8*)&Kc[((kb * 2 + 1) * 64 + lane) * 8];
                    s0 = __builtin_amdgcn_mfma_f32_16x16x32_bf16(qf[kb], k0f, s0, 0, 0, 0);
                    s1 = __builtin_amdgcn_mfma_f32_16x16x32_bf16(qf[kb], k1f, s1, 0, 0, 0);
                }
#pragma unroll
                for (int r = 0; r < 4; ++r) { s0[r] *= scale; s1[r] *= scale; }
                if (k0 + 31 > q0 + (w << 4)) {  // diagonal tiles: causal mask
#pragma unroll
                    for (int r = 0; r < 4; ++r) {
                        const int qg = q0 + w * 16 + q4 * 4 + r;
                        if (k0 + l15 > qg)      s0[r] = -INFINITY;
                        if (k0 + 16 + l15 > qg) s1[r] = -INFINITY;
                    }
                }

                // online softmax (private) + P write to wave-private LDS
                float al[4];
#pragma unroll
                for (int r = 0; r < 4; ++r) {
                    float mx = fmaxf(s0[r], s1[r]);
#pragma unroll
                    for (int off = 1; off < 16; off <<= 1) mx = fmaxf(mx, __shfl_xor(mx, off, 64));
                    const float mn = fmaxf(m_i[r], mx);
                    al[r] = __expf(m_i[r] - mn);   // first iter: exp(-inf)=0
                    m_i[r] = mn;
                    const float p0 = __expf(s0[r] - mn);
                    const float p1 = __expf(s1[r] - mn);
                    float ps = p0 + p1;
#pragma unroll
                    for (int off = 1; off < 16; off <<= 1) ps += __shfl_xor(ps, off, 64);
                    l_i[r] = l_i[r] * al[r] + ps;
                    P_lds[w][(q4 * 4 + r) * 40 + l15]      = f2b(p0);
                    P_lds[w][(q4 * 4 + r) * 40 + 16 + l15] = f2b(p1);
                }

                // rescale O (skip when all alpha == 1)
                const float alm = al[0] * al[1] * al[2] * al[3];
                if (__any(alm != 1.0f)) {
#pragma unroll
                    for (int nb = 0; nb < 32; ++nb)
#pragma unroll
                        for (int r = 0; r < 4; ++r) O[nb][r] *= al[r];
                }

                // PV-phase: my 16 rows x all 512 c (wave-private P)
                s16x8 pf = *(const s16x8*)&P_lds[w][l15 * 40 + q4 * 8];
#pragma unroll
                for (int nb = 0; nb < 32; ++nb) {
                    s16x8 vf = *(const s16x8*)&Vc[(nb * 64 + lane) * 8];
                    O[nb] = __builtin_amdgcn_mfma_f32_16x16x32_bf16(pf, vf, O[nb], 0, 0, 0);
                }
            }

            // ---- one barrier per tile: drains kt+1's DMA (already landed
            //      under compute) + protects buffer swap ----
            __syncthreads();
            unsigned short* t;
            t = Kc; Kc = Kn; Kn = t;
            t = Vc; Vc = Vn; Vn = t;
        }

        // ---- epilogue: O /= l, store bf16 (all state private) ----
        float inv[4];
#pragma unroll
        for (int r = 0; r < 4; ++r) inv[r] = 1.0f / l_i[r];
#pragma unroll
        for (int r = 0; r < 4; ++r) {
            const long rowbase = ((long)bh * S_LEN + q0 + w * 16 + q4 * 4 + r) * 512;
#pragma unroll
            for (int nb = 0; nb < 32; ++nb)
                attn_out[rowbase + nb * 16 + l15] = f2b(O[nb][r] * inv[r]);
        }
    }
}

// ---------------------------------------------------------------------------
extern "C" void kernel_launch(void* const* d_in, const int* in_sizes, int n_in,
                              void* d_out, int out_size, void* d_ws, size_t ws_size,
                              hipStream_t stream)
{
    (void)in_sizes; (void)n_in; (void)out_size; (void)ws_size;
    const float* hs_f       = (const float*)d_in[0];
    const int*   pos        = (const int*)d_in[1];
    // d_in[2] = attention_mask (causal, recomputed analytically) - unused
    const float* Wq_down_f  = (const float*)d_in[3];
    const float* q_ln_w_f   = (const float*)d_in[4];
    const float* Wq_up_f    = (const float*)d_in[5];
    const float* Wkv_down_f = (const float*)d_in[6];
    const float* Wkv_up_f   = (const float*)d_in[7];
    const float* Wo_f       = (const float*)d_in[8];
    float* out = (float*)d_out;

    // workspace layout (bf16 elements). out2 aliases q (dead after step 7).
    unsigned short* ws    = (unsigned short*)d_ws;
    unsigned short* ql    = ws;                        // 4096*1536
    unsigned short* q     = ql    + 4096L * 1536;      // 4096*3072
    unsigned short* out2  = q;                         // 4096*2048 (alias)
    unsigned short* ckv   = q     + 4096L * 3072;      // 4096*576
    unsigned short* krope = ckv   + 4096L * 576;       // 4096*64
    unsigned short* qrope = krope + 4096L * 64;        // 32*2048*64
    unsigned short* qabsT = qrope + 32L * 2048 * 64;   // 16*512*128
    unsigned short* qabs  = qabsT + 16L * 512 * 128;   // 32*2048*512
    unsigned short* attno = qabs  + 32L * 2048 * 512;  // 32*2048*512
    unsigned short* hs    = attno + 32L * 2048 * 512;  // 4096*2048
    unsigned short* Wqd   = hs    + 4096L * 2048;      // 1536*2048
    unsigned short* qlnw  = Wqd   + 1536L * 2048;      // 1536
    unsigned short* Wqu   = qlnw  + 1536;              // 3072*1536
    unsigned short* Wkvd  = Wqu   + 3072L * 1536;      // 576*2048
    unsigned short* Wkvu  = Wkvd  + 576L * 2048;       // 16*256*512
    unsigned short* Wob   = Wkvu  + 16L * 256 * 512;   // 2048*2048
    unsigned short* VTg   = Wob   + 2048L * 2048;      // 2*512*2048

    // 0) fp32 -> bf16 input conversion
    f32_to_bf16<<<4096, 256, 0, stream>>>(hs_f,       hs,   4096L * 2048);
    f32_to_bf16<<<3072, 256, 0, stream>>>(Wq_down_f,  Wqd,  1536L * 2048);
    f32_to_bf16<<<2,    256, 0, stream>>>(q_ln_w_f,   qlnw, 1536L);
    f32_to_bf16<<<4096, 256, 0, stream>>>(Wq_up_f,    Wqu,  3072L * 1536);
    f32_to_bf16<<<1152, 256, 0, stream>>>(Wkv_down_f, Wkvd, 576L * 2048);
    f32_to_bf16<<<2048, 256, 0, stream>>>(Wkv_up_f,   Wkvu, 16L * 256 * 512);
    f32_to_bf16<<<4096, 256, 0, stream>>>(Wo_f,       Wob,  2048L * 2048);

    // 1) ql = hs @ Wq_down^T   (4096x1536, K=2048)
    gemm128<unsigned short><<<dim3(32, 12, 1), 256, 0, stream>>>(hs, Wqd, ql,
        2048, 2048, 2048, 1536, 1536, 0, 0, 0, 0, 0, 0);
    // 2) RMSNorm(ql)
    rmsnorm_k<<<4096, 256, 0, stream>>>(ql, qlnw);
    // 3) q = ql @ Wq_up^T      (4096x3072, K=1536)
    gemm128<unsigned short><<<dim3(32, 24, 1), 256, 0, stream>>>(ql, Wqu, q,
        1536, 1536, 1536, 3072, 3072, 0, 0, 0, 0, 0, 0);
    // 4) ckv = hs @ Wkv_down^T (2048x576, K=2048); Nlim guards last tile
    gemm128<unsigned short><<<dim3(32, 5, 1), 256, 0, stream>>>(hs, Wkvd, ckv,
        2048, 2048, 2048, 576, 576, 0, 0, 0, 0, 0, 0);
    // 5) RoPE on q (per head) and k
    rope_k<<<4096, 512, 0, stream>>>(q, ckv, pos, qrope, krope);
    // 5b) VT_g[b][c][key] = ckv[b][key][c]
    transpose_ckv<<<dim3(32, 8, 2), 256, 0, stream>>>(ckv, VTg);
    // 6) transpose q_absorb -> (h, c, n)
    transpose_qabsorb<<<4096, 256, 0, stream>>>(Wkvu, qabsT);
    // 7) q_abs[b,h] = q_nope[b,h] @ q_absorbT[h]^T  (2048x512, K=128), batched 32
    gemm128<unsigned short><<<dim3(16, 4, 32), 256, 0, stream>>>(q, qabsT, qabs,
        128, 3072, 128, 512, 512,
        2048L * 3072, 192, 0, 512L * 128, 16L * 2048 * 512, 2048L * 512);
    // 8) MFMA flash attention -> attn_out (B,NH,S,512): 2-phase pipelined,
    //    128-row q-blocks, 8 waves, 1 block/CU (149.5 KB LDS), 68 tiles/block
    flash_mfma<<<dim3(32, 8, 1), 512, 0, stream>>>(qabs, qrope, ckv, krope, VTg, attno);
    // 9) out2 = attn_out @ out_absorb^T per head (2048x128, K=512), batched 32
    gemm128<unsigned short><<<dim3(16, 1, 32), 256, 0, stream>>>(attno, Wkvu + 128L * 512, out2,
        512, 512, 512, 2048, 128,
        16L * 2048 * 512, 2048L * 512, 0, 256L * 512, 2048L * 2048, 128);
    // 10) out = out2 @ Wo^T    (4096x2048, K=2048), fp32 output
    gemm128<float><<<dim3(32, 16, 1), 256, 0, stream>>>(out2, Wob, out,
        2048, 2048, 2048, 2048, 2048, 0, 0, 0, 0, 0, 0);
}